// Round 2
// baseline (1106.109 us; speedup 1.0000x reference)
//
#include <hip/hip_runtime.h>

// AttentionLayer: x (192,1024,128) f32; W_qkv (128,384) f32; W_out (128,128) f32;
// b_out (128) f32. H=8 heads x hd=16. Output (192,1024,128) f32.
//
// Math (matching reference):
//   qkv = x @ W_qkv ; q,k,v = split
//   qs,ks = l2norm over head dim (16), eps 1e-12
//   kvs[b,h,m,d]   = sum_l ks[b,l,h,m] * vs[b,l,h,d]
//   ks_sum[b,h,m]  = sum_l ks[b,l,h,m]
//   pre = (qs.kvs + N*vs) / (qs.ks_sum + N)
//   out = pre @ W_out + b_out
#define NBATCH 192
#define SEQ    1024
#define DIM    128
#define NH     8
#define RG     8          // rows per group
#define TILES  16         // 64-row tiles per batch

// ---- workspace layout (floats) ----
// kvs_ws   : 192*8*16*16 = 393216 floats
// kssum_ws : 192*128     =  24576 floats   (total 417792 floats = 1.7 MB)
#define KVS_FLOATS   393216
#define TOTAL_ZERO   417792

// ---------------- kernel 0: zero accumulators ----------------
__global__ __launch_bounds__(256) void k0_zero(float* __restrict__ p) {
    p[blockIdx.x * 256 + threadIdx.x] = 0.0f;
}

// ---------------- kernel 1: k,v GEMM -> normalize k -> kvs & ks_sum ----------------
__global__ __launch_bounds__(256) void k1_kv(const float* __restrict__ x,
                                             const float* __restrict__ Wqkv,
                                             float* __restrict__ kvs_ws,
                                             float* __restrict__ kssum_ws) {
    __shared__ float xs[RG * DIM];     // 4 KB
    __shared__ float knb[RG][DIM];     // 4 KB (normalized k)
    __shared__ float vb[RG][DIM];      // 4 KB (v)

    const int b    = blockIdx.x >> 4;
    const int tile = blockIdx.x & 15;
    const int t    = threadIdx.x;
    const int rowbase = tile * (RG * RG);   // 64 rows per block

    // thread's W column: k col t (t<128) or v col t-128 (t>=128); both = Wqkv col 128+t
    const float* wp = Wqkv + 128 + t;

    // kvs ownership: thread t -> (h, m, 8 d's)
    const int h_t  = t >> 5;
    const int m_t  = (t >> 1) & 15;
    const int d0_t = (t & 1) * 8;

    float ksum = 0.0f;
    float kvsacc[8];
#pragma unroll
    for (int i = 0; i < 8; ++i) kvsacc[i] = 0.0f;

    for (int g = 0; g < 8; ++g) {
        __syncthreads();   // previous iteration's readers of xs/knb/vb are done
        {
            int r = t >> 5, j4 = t & 31;   // 8 rows x 32 float4
            const float4 v4 = *reinterpret_cast<const float4*>(
                x + (size_t)(b * SEQ + rowbase + g * RG + r) * DIM + j4 * 4);
            *reinterpret_cast<float4*>(&xs[r * DIM + j4 * 4]) = v4;
        }
        __syncthreads();

        float acc[RG];
#pragma unroll
        for (int r = 0; r < RG; ++r) acc[r] = 0.0f;
#pragma unroll 8
        for (int j = 0; j < DIM; ++j) {
            float w = wp[j * 384];
#pragma unroll
            for (int r = 0; r < RG; ++r) acc[r] = fmaf(xs[r * DIM + j], w, acc[r]);
        }

        if (t < 128) {                 // k columns: normalize per head (16 lanes/head)
#pragma unroll
            for (int r = 0; r < RG; ++r) {
                float ssq = acc[r] * acc[r];
                ssq += __shfl_xor(ssq, 1); ssq += __shfl_xor(ssq, 2);
                ssq += __shfl_xor(ssq, 4); ssq += __shfl_xor(ssq, 8);
                float kn = acc[r] / fmaxf(sqrtf(ssq), 1e-12f);
                ksum += kn;
                knb[r][t] = kn;
            }
        } else {                       // v columns
#pragma unroll
            for (int r = 0; r < RG; ++r) vb[r][t - 128] = acc[r];
        }
        __syncthreads();

        // kvs partial: kvs[h][m][d] += kn[r][16h+m] * v[r][16h+d]
#pragma unroll
        for (int r = 0; r < RG; ++r) {
            float kv = knb[r][h_t * 16 + m_t];
#pragma unroll
            for (int i = 0; i < 8; ++i)
                kvsacc[i] = fmaf(kv, vb[r][h_t * 16 + d0_t + i], kvsacc[i]);
        }
    }

#pragma unroll
    for (int i = 0; i < 8; ++i)
        atomicAdd(&kvs_ws[b * 2048 + h_t * 256 + m_t * 16 + d0_t + i], kvsacc[i]);
    if (t < 128) atomicAdd(&kssum_ws[b * 128 + t], ksum);
}

// ---------------- kernel 2: q,v GEMM -> epilogue -> out projection ----------------
__global__ __launch_bounds__(256) void k2_out(const float* __restrict__ x,
                                              const float* __restrict__ Wqkv,
                                              const float* __restrict__ Wout,
                                              const float* __restrict__ bout,
                                              const float* __restrict__ kvs_ws,
                                              const float* __restrict__ kssum_ws,
                                              float* __restrict__ out) {
    __shared__ float xs[RG * DIM];     // 4 KB
    __shared__ float qsb[RG][DIM];     // 4 KB (normalized q)
    __shared__ float vbuf[RG][DIM];    // 4 KB
    __shared__ float preb[RG][DIM];    // 4 KB
    __shared__ float kvsl[2048];       // 8 KB (kvs for this b)
    __shared__ float invn[RG][NH];     // 1/(qs.ks_sum + N) per row,head

    const int b    = blockIdx.x >> 4;
    const int tile = blockIdx.x & 15;
    const int t    = threadIdx.x;
    const int rowbase = tile * (RG * RG);

#pragma unroll
    for (int i = 0; i < 8; ++i) kvsl[i * 256 + t] = kvs_ws[b * 2048 + i * 256 + t];
    const float kss_t = (t < 128) ? kssum_ws[b * 128 + t] : 0.0f;

    // thread's W column: q col t (t<128) or v col 256+(t-128)
    const float* wp = Wqkv + t + ((t >> 7) << 7);

    const int c    = t & 127;          // output column for pre/proj phases
    const int rsel = t >> 7;           // 0: rows 0-3, 1: rows 4-7
    const int h_c  = c >> 4, d_c = c & 15;
    const float bo = bout[c];

    for (int g = 0; g < 8; ++g) {
        __syncthreads();
        {
            int r = t >> 5, j4 = t & 31;
            const float4 v4 = *reinterpret_cast<const float4*>(
                x + (size_t)(b * SEQ + rowbase + g * RG + r) * DIM + j4 * 4);
            *reinterpret_cast<float4*>(&xs[r * DIM + j4 * 4]) = v4;
        }
        __syncthreads();

        float acc[RG];
#pragma unroll
        for (int r = 0; r < RG; ++r) acc[r] = 0.0f;
#pragma unroll 8
        for (int j = 0; j < DIM; ++j) {
            float w = wp[j * 384];
#pragma unroll
            for (int r = 0; r < RG; ++r) acc[r] = fmaf(xs[r * DIM + j], w, acc[r]);
        }

        if (t < 128) {                 // q columns
#pragma unroll
            for (int r = 0; r < RG; ++r) {
                float ssq = acc[r] * acc[r];
                ssq += __shfl_xor(ssq, 1); ssq += __shfl_xor(ssq, 2);
                ssq += __shfl_xor(ssq, 4); ssq += __shfl_xor(ssq, 8);
                float tt = acc[r] * kss_t;
                tt += __shfl_xor(tt, 1); tt += __shfl_xor(tt, 2);
                tt += __shfl_xor(tt, 4); tt += __shfl_xor(tt, 8);
                float den_inv = 1.0f / fmaxf(sqrtf(ssq), 1e-12f);
                qsb[r][t] = acc[r] * den_inv;
                float inr = 1.0f / (tt * den_inv + (float)SEQ);
                if ((t & 15) == 0) invn[r][t >> 4] = inr;
            }
        } else {
#pragma unroll
            for (int r = 0; r < RG; ++r) vbuf[r][t - 128] = acc[r];
        }
        __syncthreads();

        // pre[r][c] = invn[r][h] * (sum_m qs[r][16h+m]*kvs[h][m][d] + N*v[r][c])
#pragma unroll
        for (int k = 0; k < 4; ++k) {
            int r = rsel * 4 + k;
            float s = 0.0f;
#pragma unroll
            for (int m = 0; m < 16; ++m)
                s = fmaf(qsb[r][h_c * 16 + m], kvsl[h_c * 256 + m * 16 + d_c], s);
            preb[r][c] = invn[r][h_c] * (s + (float)SEQ * vbuf[r][c]);
        }
        __syncthreads();

        // out projection: out[r][c] = sum_j pre[r][j]*Wout[j][c] + b[c]
        float oacc[4];
#pragma unroll
        for (int k = 0; k < 4; ++k) oacc[k] = 0.0f;
#pragma unroll 4
        for (int j = 0; j < DIM; ++j) {
            float w = Wout[j * 128 + c];
#pragma unroll
            for (int k = 0; k < 4; ++k)
                oacc[k] = fmaf(preb[rsel * 4 + k][j], w, oacc[k]);
        }
#pragma unroll
        for (int k = 0; k < 4; ++k) {
            int row = rowbase + g * RG + rsel * 4 + k;
            out[(size_t)(b * SEQ + row) * DIM + c] = oacc[k] + bo;
        }
    }
}

extern "C" void kernel_launch(void* const* d_in, const int* in_sizes, int n_in,
                              void* d_out, int out_size, void* d_ws, size_t ws_size,
                              hipStream_t stream) {
    const float* x    = (const float*)d_in[0];
    const float* Wqkv = (const float*)d_in[1];
    const float* Wout = (const float*)d_in[2];
    const float* bout = (const float*)d_in[3];
    float* out = (float*)d_out;

    float* kvs_ws   = (float*)d_ws;
    float* kssum_ws = kvs_ws + KVS_FLOATS;

    k0_zero<<<dim3(TOTAL_ZERO / 256), dim3(256), 0, stream>>>(kvs_ws);
    k1_kv<<<dim3(NBATCH * TILES), dim3(256), 0, stream>>>(x, Wqkv, kvs_ws, kssum_ws);
    k2_out<<<dim3(NBATCH * TILES), dim3(256), 0, stream>>>(x, Wqkv, Wout, bout,
                                                           kvs_ws, kssum_ws, out);
}

// Round 3
// 310.968 us; speedup vs baseline: 3.5570x; 3.5570x over previous
//
#include <hip/hip_runtime.h>

// AttentionLayer, MFMA bf16 version.
// x (192,1024,128) f32; W_qkv (128,384) f32; W_out (128,128) f32; b_out (128) f32.
// out (192,1024,128) f32. H=8 heads x hd=16, N=SEQ=1024.
#define NBATCH 192
#define SEQ    1024
#define DIM    128
#define NH     8
#define EPS    1e-12f

typedef short bf16x8 __attribute__((ext_vector_type(8)));
typedef float f32x4  __attribute__((ext_vector_type(4)));

// ws layout: kvs 393216 f32, kssum 24576 f32, then bf16 wsWT[4][128][128] ([q,k,v,out], [n][c])
#define KVS_F  393216
#define ZERO_F 417792

static __device__ __forceinline__ unsigned short f2bf(float f) {
    unsigned u = __builtin_bit_cast(unsigned, f);
    u += 0x7fff + ((u >> 16) & 1);          // RTNE
    return (unsigned short)(u >> 16);
}

template <int CTRL>
static __device__ __forceinline__ float dpp_add(float v) {
    int j = __builtin_amdgcn_mov_dpp(__builtin_bit_cast(int, v), CTRL, 0xf, 0xf, false);
    return v + __builtin_bit_cast(float, j);
}
// sum over the 16 lanes of a DPP row (= over n15); all lanes get the result
static __device__ __forceinline__ float r16sum(float v) {
    v = dpp_add<0xB1>(v);    // quad_perm [1,0,3,2]  : xor1
    v = dpp_add<0x4E>(v);    // quad_perm [2,3,0,1]  : xor2
    v = dpp_add<0x141>(v);   // row_half_mirror      : pairs 4-groups
    v = dpp_add<0x140>(v);   // row_mirror           : pairs 8-groups
    return v;
}

// strip: [row][32 els], granule(8 el)-swizzled by row&3. addr in shorts.
static __device__ __forceinline__ int strip_addr(int row, int el) {
    return row * 32 + ((((el >> 3) ^ (row & 3)) << 3) | (el & 7));
}

// stage 128x128 bf16 [n][c] from global into LDS with granule swizzle (512 threads)
static __device__ __forceinline__ void stage_w(unsigned short* lds,
                                               const unsigned short* __restrict__ gT, int t) {
#pragma unroll
    for (int i = 0; i < 4; ++i) {
        int idx = i * 512 + t, n = idx >> 4, gr = idx & 15;
        uint4 v = *reinterpret_cast<const uint4*>(gT + n * 128 + gr * 8);
        *reinterpret_cast<uint4*>(lds + n * 128 + ((gr ^ (n & 15)) << 3)) = v;
    }
}

// b-frag: lane(q,n15) gets W[k=ks*32+q*8+j][n=ct*16+n15]
static __device__ __forceinline__ bf16x8 wfrag(const unsigned short* lds, int ct, int ks,
                                               int q, int n15) {
    return *reinterpret_cast<const bf16x8*>(
        lds + (ct * 16 + n15) * 128 + ((((ks << 2) + q) ^ n15) << 3));
}

static __device__ __forceinline__ uint2 pack4(float a, float b, float c, float d) {
    uint2 r;
    r.x = (unsigned)f2bf(a) | ((unsigned)f2bf(b) << 16);
    r.y = (unsigned)f2bf(c) | ((unsigned)f2bf(d) << 16);
    return r;
}

static __device__ __forceinline__ bf16x8 cvt8(float4 a, float4 b) {
    bf16x8 r;
    r[0] = (short)f2bf(a.x); r[1] = (short)f2bf(a.y); r[2] = (short)f2bf(a.z); r[3] = (short)f2bf(a.w);
    r[4] = (short)f2bf(b.x); r[5] = (short)f2bf(b.y); r[6] = (short)f2bf(b.z); r[7] = (short)f2bf(b.w);
    return r;
}

// ---------------- k0: zero accumulators + transpose/convert weights ----------------
__global__ __launch_bounds__(256) void k0_prep(const float* __restrict__ Wqkv,
                                               const float* __restrict__ Wout,
                                               float* __restrict__ zero_p,
                                               unsigned short* __restrict__ wsWT) {
    int bid = blockIdx.x, t = threadIdx.x;
    if (bid < 1632) { zero_p[bid * 256 + t] = 0.0f; return; }
    int i = (bid - 1632) * 256 + t;        // 0..65535
    int which = i >> 14, e = i & 16383;
    int n = e & 127, c = e >> 7;           // consecutive t -> consecutive n (coalesced read)
    float v = (which < 3) ? Wqkv[c * 384 + which * 128 + n] : Wout[c * 128 + n];
    wsWT[which * 16384 + n * 128 + c] = f2bf(v);
}

// ---------------- k1: k,v GEMM -> normalize k -> kvs & ks_sum ----------------
__global__ __launch_bounds__(512, 4) void k1_kv(const float* __restrict__ x,
                                                const unsigned short* __restrict__ wsWT,
                                                float* __restrict__ kvs_ws,
                                                float* __restrict__ kssum_ws) {
    __shared__ unsigned short lds[40960];  // wk 16384 | wv 16384 | strips 8192  (80 KB)
    unsigned short* wk = lds;
    unsigned short* wv = lds + 16384;
    int t = threadIdx.x, w = t >> 6, lane = t & 63, q = lane >> 4, n15 = lane & 15;
    int b = blockIdx.x >> 2, seg = blockIdx.x & 3;

    stage_w(wk, wsWT + 1 * 16384, t);      // W_k^T
    stage_w(wv, wsWT + 2 * 16384, t);      // W_v^T
    unsigned short* knS = lds + 32768 + w * 1024;   // [16 m][32 l]
    unsigned short* vS  = knS + 512;                // [16 d][32 l]

    // a-frags: rows seg*256 + w*32 + rs*16 + n15
    bf16x8 ah[2][4];
#pragma unroll
    for (int rs = 0; rs < 2; ++rs) {
        int row = seg * 256 + w * 32 + rs * 16 + n15;
        const float* xr = x + (size_t)(b * SEQ + row) * DIM;
#pragma unroll
        for (int ks = 0; ks < 4; ++ks) {
            float4 p0 = *reinterpret_cast<const float4*>(xr + ks * 32 + q * 8);
            float4 p1 = *reinterpret_cast<const float4*>(xr + ks * 32 + q * 8 + 4);
            ah[rs][ks] = cvt8(p0, p1);
        }
    }
    __syncthreads();

    f32x4 kvsacc[8];
    float ksum[8];
#pragma unroll
    for (int h = 0; h < 8; ++h) { kvsacc[h] = (f32x4){0,0,0,0}; ksum[h] = 0.f; }

#pragma unroll
    for (int ct = 0; ct < 8; ++ct) {
        f32x4 ka[2] = {(f32x4){0,0,0,0}, (f32x4){0,0,0,0}};
        f32x4 va[2] = {(f32x4){0,0,0,0}, (f32x4){0,0,0,0}};
#pragma unroll
        for (int ks = 0; ks < 4; ++ks) {
            bf16x8 kb = wfrag(wk, ct, ks, q, n15);
            bf16x8 vb = wfrag(wv, ct, ks, q, n15);
#pragma unroll
            for (int rs = 0; rs < 2; ++rs) {
                ka[rs] = __builtin_amdgcn_mfma_f32_16x16x32_bf16(ah[rs][ks], kb, ka[rs], 0, 0, 0);
                va[rs] = __builtin_amdgcn_mfma_f32_16x16x32_bf16(ah[rs][ks], vb, va[rs], 0, 0, 0);
            }
        }
        // normalize k rows (reduce over n15 = head dim), stash kn & v into strips
#pragma unroll
        for (int rs = 0; rs < 2; ++rs) {
            float kn[4];
#pragma unroll
            for (int r = 0; r < 4; ++r) {
                float val = ka[rs][r];
                float ssq = r16sum(val * val);
                float di  = 1.0f / fmaxf(sqrtf(ssq), EPS);
                kn[r] = val * di;
                ksum[ct] += kn[r];
            }
            *reinterpret_cast<uint2*>(knS + strip_addr(n15, rs * 16 + q * 4)) =
                pack4(kn[0], kn[1], kn[2], kn[3]);
            *reinterpret_cast<uint2*>(vS + strip_addr(n15, rs * 16 + q * 4)) =
                pack4(va[rs][0], va[rs][1], va[rs][2], va[rs][3]);
        }
        // kvs[h][m][d] += kn^T (m x l=32) . v (l x d)  — one K=32 MFMA
        bf16x8 aK = *reinterpret_cast<const bf16x8*>(knS + strip_addr(n15, q * 8));
        bf16x8 bV = *reinterpret_cast<const bf16x8*>(vS + strip_addr(n15, q * 8));
        kvsacc[ct] = __builtin_amdgcn_mfma_f32_16x16x32_bf16(aK, bV, kvsacc[ct], 0, 0, 0);
    }

    // ks_sum: reduce over q-groups (rows), then atomics from lanes 0..15
#pragma unroll
    for (int ct = 0; ct < 8; ++ct) {
        float s = ksum[ct];
        s += __shfl_xor(s, 16); s += __shfl_xor(s, 32);
        if (lane < 16) atomicAdd(&kssum_ws[b * 128 + ct * 16 + n15], s);
    }

    // block-level kvs reduction over 8 waves, then one atomic per element
    __syncthreads();
    float* red = reinterpret_cast<float*>(lds);    // 8 waves x 2048 f32 = 64 KB (wk+wv area)
#pragma unroll
    for (int ct = 0; ct < 8; ++ct)
#pragma unroll
        for (int r = 0; r < 4; ++r)
            red[w * 2048 + ct * 256 + (q * 4 + r) * 16 + n15] = kvsacc[ct][r];
    __syncthreads();
#pragma unroll
    for (int i = 0; i < 4; ++i) {
        int el = i * 512 + t;
        float s = 0.f;
#pragma unroll
        for (int ww = 0; ww < 8; ++ww) s += red[ww * 2048 + el];
        atomicAdd(&kvs_ws[b * 2048 + el], s);
    }
}

// ---------------- k2: q,v GEMM -> fold norms -> num MFMA -> out projection ----------------
__global__ __launch_bounds__(512, 2) void k2_out(const float* __restrict__ x,
                                                 const unsigned short* __restrict__ wsWT,
                                                 const float* __restrict__ kvs_ws,
                                                 const float* __restrict__ kssum_ws,
                                                 const float* __restrict__ bout,
                                                 float* __restrict__ out) {
    __shared__ unsigned short lds[57344];  // wbuf 16384 | kvsT 4096 | qsS 4096 | tile 32768 (112 KB)
    unsigned short* wbuf = lds;
    unsigned short* kvsT = lds + 16384;    // [h*16+d][32 mpad]
    unsigned short* qsS  = lds + 20480;    // per-wave [16 row][32 mpad]
    unsigned short* tile = lds + 24576;    // [256 row][128 c] bf16, granule-swizzled by row&15
    int t = threadIdx.x, w = t >> 6, lane = t & 63, q = lane >> 4, n15 = lane & 15;
    int b = blockIdx.x >> 2, seg = blockIdx.x & 3, rowbase = seg * 256;

    stage_w(wbuf, wsWT + 2 * 16384, t);    // W_v^T first
    {   // build kvsT (bf16, transposed [h][d][m], m>=16 zero)
        int row = t >> 2, part = t & 3, h = row >> 4, d = row & 15;
        unsigned es[8];
#pragma unroll
        for (int j = 0; j < 8; j += 2) {
            int m0 = part * 8 + j;
            unsigned lo = (m0     < 16) ? f2bf(kvs_ws[b * 2048 + h * 256 + m0 * 16 + d])      : 0;
            unsigned hi = (m0 + 1 < 16) ? f2bf(kvs_ws[b * 2048 + h * 256 + (m0 + 1) * 16 + d]) : 0;
            es[j] = lo | (hi << 16);
        }
        uint4 v = {es[0], es[2], es[4], es[6]};
        *reinterpret_cast<uint4*>(kvsT + row * 32 + (((part ^ (row & 3)) << 3))) = v;
    }
    {   // zero own qs-strip pad (els 16..31 of each of 16 rows)
        unsigned short* s = qsS + w * 512;
        uint2 z = {0, 0};
        *reinterpret_cast<uint2*>(s + strip_addr(n15, 16 + q * 4)) = z;
    }
    float kss[8];
#pragma unroll
    for (int h = 0; h < 8; ++h) kss[h] = kssum_ws[b * 128 + h * 16 + n15];

    bf16x8 ah[2][4];
#pragma unroll
    for (int rs = 0; rs < 2; ++rs) {
        int row = rowbase + w * 32 + rs * 16 + n15;
        const float* xr = x + (size_t)(b * SEQ + row) * DIM;
#pragma unroll
        for (int ks = 0; ks < 4; ++ks) {
            float4 p0 = *reinterpret_cast<const float4*>(xr + ks * 32 + q * 8);
            float4 p1 = *reinterpret_cast<const float4*>(xr + ks * 32 + q * 8 + 4);
            ah[rs][ks] = cvt8(p0, p1);
        }
    }
    __syncthreads();

    // ---- V GEMM ----
    f32x4 vacc[2][8];
#pragma unroll
    for (int rs = 0; rs < 2; ++rs)
#pragma unroll
        for (int h = 0; h < 8; ++h) vacc[rs][h] = (f32x4){0,0,0,0};
#pragma unroll
    for (int ct = 0; ct < 8; ++ct)
#pragma unroll
        for (int ks = 0; ks < 4; ++ks) {
            bf16x8 bb = wfrag(wbuf, ct, ks, q, n15);
#pragma unroll
            for (int rs = 0; rs < 2; ++rs)
                vacc[rs][ct] = __builtin_amdgcn_mfma_f32_16x16x32_bf16(ah[rs][ks], bb, vacc[rs][ct], 0, 0, 0);
        }
    __syncthreads();
    stage_w(wbuf, wsWT + 0, t);            // W_q^T
    __syncthreads();

    // ---- Q GEMM ----
    f32x4 qacc[2][8];
#pragma unroll
    for (int rs = 0; rs < 2; ++rs)
#pragma unroll
        for (int h = 0; h < 8; ++h) qacc[rs][h] = (f32x4){0,0,0,0};
#pragma unroll
    for (int ct = 0; ct < 8; ++ct)
#pragma unroll
        for (int ks = 0; ks < 4; ++ks) {
            bf16x8 bb = wfrag(wbuf, ct, ks, q, n15);
#pragma unroll
            for (int rs = 0; rs < 2; ++rs)
                qacc[rs][ct] = __builtin_amdgcn_mfma_f32_16x16x32_bf16(ah[rs][ks], bb, qacc[rs][ct], 0, 0, 0);
        }

    // ---- fold norms, numerator MFMA, write pre tile ----
    unsigned short* myS = qsS + w * 512;
#pragma unroll
    for (int rs = 0; rs < 2; ++rs)
#pragma unroll
        for (int h = 0; h < 8; ++h) {
            float pv[4];
#pragma unroll
            for (int r = 0; r < 4; ++r) {
                float val = qacc[rs][h][r];
                float ssq = r16sum(val * val);
                float tt  = r16sum(val * kss[h]);
                float di  = 1.0f / fmaxf(sqrtf(ssq), EPS);
                float inv = 1.0f / (tt * di + (float)SEQ);
                pv[r] = val * di * inv;                 // qs * invn
                vacc[rs][h][r] *= (float)SEQ * inv;     // N * v * invn
            }
#pragma unroll
            for (int r = 0; r < 4; ++r)
                myS[strip_addr(q * 4 + r, n15)] = f2bf(pv[r]);
            bf16x8 aq = *reinterpret_cast<const bf16x8*>(myS + strip_addr(n15, q * 8));
            bf16x8 bk = *reinterpret_cast<const bf16x8*>(kvsT + strip_addr(h * 16 + n15, q * 8));
            vacc[rs][h] = __builtin_amdgcn_mfma_f32_16x16x32_bf16(aq, bk, vacc[rs][h], 0, 0, 0); // = pre
#pragma unroll
            for (int r = 0; r < 4; ++r) {
                int rt = w * 32 + rs * 16 + q * 4 + r;
                int colg = h * 2 + (n15 >> 3);
                tile[rt * 128 + (((colg ^ (rt & 15)) << 3) | (n15 & 7))] = f2bf(vacc[rs][h][r]);
            }
        }

    __syncthreads();
    stage_w(wbuf, wsWT + 3 * 16384, t);    // W_out^T
    __syncthreads();

    // ---- out projection ----
    bf16x8 ap[2][4];
#pragma unroll
    for (int rs = 0; rs < 2; ++rs)
#pragma unroll
        for (int ks = 0; ks < 4; ++ks) {
            int rt = w * 32 + rs * 16 + n15;
            ap[rs][ks] = *reinterpret_cast<const bf16x8*>(
                tile + rt * 128 + ((((ks << 2) + q) ^ (rt & 15)) << 3));
        }
    f32x4 oacc[2][8];
#pragma unroll
    for (int rs = 0; rs < 2; ++rs)
#pragma unroll
        for (int h = 0; h < 8; ++h) oacc[rs][h] = (f32x4){0,0,0,0};
#pragma unroll
    for (int ct = 0; ct < 8; ++ct)
#pragma unroll
        for (int ks = 0; ks < 4; ++ks) {
            bf16x8 bb = wfrag(wbuf, ct, ks, q, n15);
#pragma unroll
            for (int rs = 0; rs < 2; ++rs)
                oacc[rs][ct] = __builtin_amdgcn_mfma_f32_16x16x32_bf16(ap[rs][ks], bb, oacc[rs][ct], 0, 0, 0);
        }
#pragma unroll
    for (int ct = 0; ct < 8; ++ct) {
        float bo = bout[ct * 16 + n15];
#pragma unroll
        for (int rs = 0; rs < 2; ++rs)
#pragma unroll
            for (int r = 0; r < 4; ++r) {
                int row = rowbase + w * 32 + rs * 16 + q * 4 + r;
                out[(size_t)(b * SEQ + row) * DIM + ct * 16 + n15] = oacc[rs][ct][r] + bo;
            }
    }
}

extern "C" void kernel_launch(void* const* d_in, const int* in_sizes, int n_in,
                              void* d_out, int out_size, void* d_ws, size_t ws_size,
                              hipStream_t stream) {
    const float* x    = (const float*)d_in[0];
    const float* Wqkv = (const float*)d_in[1];
    const float* Wout = (const float*)d_in[2];
    const float* bout = (const float*)d_in[3];
    float* out = (float*)d_out;

    float* kvs_ws   = (float*)d_ws;
    float* kssum_ws = kvs_ws + KVS_F;
    unsigned short* wsWT = (unsigned short*)((char*)d_ws + (size_t)ZERO_F * 4);

    k0_prep<<<dim3(1888), dim3(256), 0, stream>>>(Wqkv, Wout, kvs_ws, wsWT);
    k1_kv<<<dim3(768), dim3(512), 0, stream>>>(x, wsWT, kvs_ws, kssum_ws);
    k2_out<<<dim3(768), dim3(512), 0, stream>>>(x, wsWT, kvs_ws, kssum_ws, bout, out);
}